// Round 15
// baseline (83.276 us; speedup 1.0000x reference)
//
#include <hip/hip_runtime.h>
#include <hip/hip_bf16.h>

typedef __attribute__((ext_vector_type(8))) short short8;
typedef __attribute__((ext_vector_type(4))) float f32x4;

#define IN_F 512
#define OUT_F 512
#define BK 64
#define PHI_STEPS 64
#define NSTEPS 72
#define PAN 64                           // A image panel = 64 rows
#define ACH 512                          // A chunks per (panel, step)
#define BCH4 1024                        // B chunks per (nt128, step)
#define NT4 4
#define BCH2 2048                        // fallback B chunks per (nt256, step)
#define NT2 2
#define PART_ELEMS (8192 * OUT_F)
#define C2 (-10.2591705f)                // -(8/3)^2 * log2(e)

// Branchless RNE f32->bf16 (finite values only)
__device__ __forceinline__ short f2bf(float f) {
  unsigned u = __builtin_bit_cast(unsigned, f);
  u += 0x7fffu + ((u >> 16) & 1u);
  return (short)(u >> 16);
}

__device__ __forceinline__ void glds16(const void* g, void* l) {
  // 16B global->LDS; LDS base wave-uniform (HW adds lane*16); global src per-lane.
  __builtin_amdgcn_global_load_lds(
      (const __attribute__((address_space(1))) unsigned int*)g,
      (__attribute__((address_space(3))) unsigned int*)l, 16, 0, 0);
}

__device__ __forceinline__ float bsrc(const float* __restrict__ w,
                                      const float* __restrict__ sb,
                                      int k, int col) {
  return (k < IN_F * 8) ? w[(size_t)k * OUT_F + col]
                        : sb[(size_t)(k - IN_F * 8) * OUT_F + col];
}

// ---- B images, 128-col tiles: per (nt,s), chunk ci=n*8+slot, slot=oct^(n&7),
//      element j -> B[k=s*64+oct*8+j][nt*128+n].
__global__ void __launch_bounds__(256) prep_b4(const float* __restrict__ w,
                                               const float* __restrict__ sb,
                                               short* __restrict__ img) {
  const int D = blockIdx.x * 256 + threadIdx.x;
  const int ci = D & (BCH4 - 1);
  const int im = D >> 10;                 // nt*NSTEPS + s
  const int s = im % NSTEPS;
  const int nt = im / NSTEPS;
  const int n = ci >> 3, slot = ci & 7;
  const int oct = slot ^ (n & 7);
  const int col = nt * 128 + n;
  short8 v;
#pragma unroll
  for (int j = 0; j < 8; ++j) v[j] = f2bf(bsrc(w, sb, s * 64 + oct * 8 + j, col));
  *(short8*)&img[(size_t)D * 8] = v;
}

// ---- fallback B images, 256-col tiles (R13 layout)
__global__ void __launch_bounds__(256) prep_b2(const float* __restrict__ w,
                                               const float* __restrict__ sb,
                                               short* __restrict__ img) {
  const int D = blockIdx.x * 256 + threadIdx.x;
  const int ci = D & (BCH2 - 1);
  const int im = D >> 11;
  const int s = im % NSTEPS;
  const int nt = im / NSTEPS;
  const int n = ci >> 3, slot = ci & 7;
  const int oct = slot ^ (n & 7);
  const int col = nt * 256 + n;
  short8 v;
#pragma unroll
  for (int j = 0; j < 8; ++j) v[j] = f2bf(bsrc(w, sb, s * 64 + oct * 8 + j, col));
  *(short8*)&img[(size_t)D * 8] = v;
}

// ---- A images: per (panel,s), chunk ci=m*8+slot, slot=oct^(m&7);
//      element j -> phi[panel*64+m][k=s*64+oct*8+j].
__global__ void __launch_bounds__(256) prep_a(const float* __restrict__ x,
                                              const float* __restrict__ rw,
                                              const float* __restrict__ rc,
                                              short* __restrict__ aimg) {
  const int D = blockIdx.x * 256 + threadIdx.x;
  const int ci = D & (ACH - 1);
  const int rest = D >> 9;
  const int s = rest % NSTEPS;
  const int pan = rest / NSTEPS;
  const int m = ci >> 3, slot = ci & 7;
  const int oct = slot ^ (m & 7);
  const int row = pan * PAN + m;
  short8 v;
  if (s < PHI_STEPS) {
    const int feat = s * 8 + oct;
    const float xv = x[(size_t)row * IN_F + feat];
    const float4 r0 = *(const float4*)(rw + feat * 8);
    const float4 r1 = *(const float4*)(rw + feat * 8 + 4);
    const float4 q0 = *(const float4*)(rc + feat * 8);
    const float4 q1 = *(const float4*)(rc + feat * 8 + 4);
    const float rwv[8] = {r0.x, r0.y, r0.z, r0.w, r1.x, r1.y, r1.z, r1.w};
    const float rcv[8] = {q0.x, q0.y, q0.z, q0.w, q1.x, q1.y, q1.z, q1.w};
#pragma unroll
    for (int j = 0; j < 8; ++j) {
      const float z = fmaf(xv, rwv[j], -rcv[j]);
      v[j] = f2bf(exp2f(C2 * z * z));
    }
  } else {
    const float* xp = x + (size_t)row * IN_F + (s - PHI_STEPS) * 64 + oct * 8;
    const float4 u0 = *(const float4*)xp, u1 = *(const float4*)(xp + 4);
    v[0] = f2bf(__cosf(u0.x)); v[1] = f2bf(__cosf(u0.y));
    v[2] = f2bf(__cosf(u0.z)); v[3] = f2bf(__cosf(u0.w));
    v[4] = f2bf(__cosf(u1.x)); v[5] = f2bf(__cosf(u1.y));
    v[6] = f2bf(__cosf(u1.z)); v[7] = f2bf(__cosf(u1.w));
  }
  *(short8*)&aimg[(size_t)D * 8] = v;
}

// out += part
__global__ void __launch_bounds__(256) reduce_add(const float* __restrict__ part,
                                                  float* __restrict__ out) {
  const int n4 = PART_ELEMS / 4;
  const float4* p4 = (const float4*)part;
  float4* o4 = (float4*)out;
  for (int i = blockIdx.x * 256 + threadIdx.x; i < n4; i += gridDim.x * 256) {
    float4 a = o4[i];
    const float4 b = p4[i];
    a.x += b.x; a.y += b.y; a.z += b.z; a.w += b.w;
    o4[i] = a;
  }
}

// ======== main GEMM v2: 128x128 tile, 4 waves of 64x64, counted vmcnt ========
template <int KS>
__global__ void __launch_bounds__(256, 2) kan_gemm(
    const short* __restrict__ aimg, const short* __restrict__ bimg,
    const float* __restrict__ bias, float* __restrict__ out,
    float* __restrict__ part) {
  constexpr int SPLC = NSTEPS / KS;
  __shared__ __align__(16) short A_lds[2][128 * BK];   // 32 KB
  __shared__ __align__(16) short B_lds[2][128 * BK];   // 32 KB (64 KB -> 2 blk/CU)

  const int t = threadIdx.x, lane = t & 63, wid = t >> 6;  // 4 waves
  const int wm = wid >> 1, wn = wid & 1;                   // 2x2 wave grid, 64x64 each
  const int l15 = lane & 15, kb = lane >> 4;
  const int mb = blockIdx.x, nt = blockIdx.y;
  const int ks = (KS > 1) ? blockIdx.z : 0;
  const int m0 = mb * 128, n0 = nt * 128, s0 = ks * SPLC;

  f32x4 acc[4][4];
#pragma unroll
  for (int i = 0; i < 4; ++i)
#pragma unroll
    for (int j = 0; j < 4; ++j) acc[i][j] = (f32x4){0.f, 0.f, 0.f, 0.f};

  auto stage = [&](int s, int buf) {           // exactly 8 glds per thread
    // A: two 64-row panels (2*mb, 2*mb+1), 4 chunks/thread
#pragma unroll
    for (int c = 0; c < 4; ++c) {
      const int p = c >> 1;
      const short* src = aimg +
          (((size_t)(2 * mb + p) * NSTEPS + s) * ACH + (c & 1) * 256 + wid * 64 + lane) * 8;
      glds16(src, &A_lds[buf][c * 2048 + wid * 512]);
    }
    // B: 4 chunks/thread
#pragma unroll
    for (int c = 0; c < 4; ++c) {
      const short* src = bimg +
          (((size_t)nt * NSTEPS + s) * BCH4 + c * 256 + wid * 64 + lane) * 8;
      glds16(src, &B_lds[buf][c * 2048 + wid * 512]);
    }
  };

  auto mfma_step = [&](int buf) {
#pragma unroll
    for (int kk = 0; kk < 2; ++kk) {
      const int sk = kk * 4 + kb;
      short8 af[4], bf[4];
#pragma unroll
      for (int mi = 0; mi < 4; ++mi) {
        const int r = wm * 64 + mi * 16 + l15;
        af[mi] = *(const short8*)&A_lds[buf][r * BK + (sk ^ (r & 7)) * 8];
      }
#pragma unroll
      for (int ni = 0; ni < 4; ++ni) {
        const int n = wn * 64 + ni * 16 + l15;
        bf[ni] = *(const short8*)&B_lds[buf][n * BK + (sk ^ (n & 7)) * 8];
      }
#pragma unroll
      for (int mi = 0; mi < 4; ++mi)
#pragma unroll
        for (int ni = 0; ni < 4; ++ni)
          acc[mi][ni] = __builtin_amdgcn_mfma_f32_16x16x32_bf16(
              af[mi], bf[ni], acc[mi][ni], 0, 0, 0);
    }
  };

  stage(s0, 0);                                 // 8 outstanding

  for (int si = 0; si < SPLC; ++si) {
    const int c = si & 1;
    if (si + 1 < SPLC) {
      stage(s0 + si + 1, c ^ 1);                // 16 outstanding
      asm volatile("s_waitcnt vmcnt(8)" ::: "memory");  // oldest 8 (step s) landed
    } else {
      asm volatile("s_waitcnt vmcnt(0)" ::: "memory");
    }
    __builtin_amdgcn_s_barrier();               // step-s tile visible to all waves
    mfma_step(c);
    __builtin_amdgcn_s_barrier();               // retire reads before overwrite
  }

  // epilogue
#pragma unroll
  for (int ni = 0; ni < 4; ++ni) {
    const int col = n0 + wn * 64 + ni * 16 + l15;
    const float bb = (KS == 1 || ks == 0) ? bias[col] : 0.f;
#pragma unroll
    for (int mi = 0; mi < 4; ++mi) {
      const int rb = m0 + wm * 64 + mi * 16 + kb * 4;
#pragma unroll
      for (int r4 = 0; r4 < 4; ++r4) {
        const size_t idx = (size_t)(rb + r4) * OUT_F + col;
        if (KS == 1 || ks == 0) out[idx] = acc[mi][ni][r4] + bb;
        else                    part[idx] = acc[mi][ni][r4];
      }
    }
  }
}

// ======== fused fallback (R13, BN=256 images) ========
template <int KS>
__global__ void __launch_bounds__(256, 2) kan_fused(
    const float* __restrict__ x, const float* __restrict__ rw,
    const float* __restrict__ rc, const float* __restrict__ bias,
    const short* __restrict__ bimg, float* __restrict__ out,
    float* __restrict__ part) {
  constexpr int SPLC = NSTEPS / KS;
  __shared__ __align__(16) short A_lds[2][64 * BK];
  __shared__ __align__(16) short B_lds[2][256 * BK];

  const int t = threadIdx.x, lane = t & 63, wid = t >> 6;
  const int l15 = lane & 15, kb = lane >> 4;
  const int m0 = blockIdx.x * 64;
  const int nt = blockIdx.y, n0 = nt * 256;
  const int ks = (KS > 1) ? blockIdx.z : 0;
  const int s0 = ks * SPLC;
  const int a_il = t & 7, a_m = t >> 3;

  f32x4 acc[4][4];
#pragma unroll
  for (int i = 0; i < 4; ++i)
#pragma unroll
    for (int j = 0; j < 4; ++j) acc[i][j] = (f32x4){0.f, 0.f, 0.f, 0.f};

  float xrA, xrB;
  float4 pr0, pr1, pc0, pc1, cA0, cA1, cB0, cB1;

  auto loadNext = [&](int s1) {
    if (s1 < PHI_STEPS) {
      const int feat = s1 * 8 + a_il;
      xrA = x[(size_t)(m0 + a_m) * IN_F + feat];
      xrB = x[(size_t)(m0 + a_m + 32) * IN_F + feat];
      pr0 = *(const float4*)(rw + feat * 8);
      pr1 = *(const float4*)(rw + feat * 8 + 4);
      pc0 = *(const float4*)(rc + feat * 8);
      pc1 = *(const float4*)(rc + feat * 8 + 4);
    } else {
      const float* xpA = x + (size_t)(m0 + a_m) * IN_F + (s1 - PHI_STEPS) * 64 + a_il * 8;
      const float* xpB = xpA + (size_t)32 * IN_F;
      cA0 = *(const float4*)xpA; cA1 = *(const float4*)(xpA + 4);
      cB0 = *(const float4*)xpB; cB1 = *(const float4*)(xpB + 4);
    }
  };

  auto writeA = [&](int s1, short* __restrict__ Ad) {
    short8 avA, avB;
    if (s1 < PHI_STEPS) {
      const float rwv[8] = {pr0.x, pr0.y, pr0.z, pr0.w, pr1.x, pr1.y, pr1.z, pr1.w};
      const float rcv[8] = {pc0.x, pc0.y, pc0.z, pc0.w, pc1.x, pc1.y, pc1.z, pc1.w};
#pragma unroll
      for (int b = 0; b < 8; ++b) {
        const float zA = fmaf(xrA, rwv[b], -rcv[b]);
        const float zB = fmaf(xrB, rwv[b], -rcv[b]);
        avA[b] = f2bf(exp2f(C2 * zA * zA));
        avB[b] = f2bf(exp2f(C2 * zB * zB));
      }
    } else {
      avA[0] = f2bf(__cosf(cA0.x)); avA[1] = f2bf(__cosf(cA0.y));
      avA[2] = f2bf(__cosf(cA0.z)); avA[3] = f2bf(__cosf(cA0.w));
      avA[4] = f2bf(__cosf(cA1.x)); avA[5] = f2bf(__cosf(cA1.y));
      avA[6] = f2bf(__cosf(cA1.z)); avA[7] = f2bf(__cosf(cA1.w));
      avB[0] = f2bf(__cosf(cB0.x)); avB[1] = f2bf(__cosf(cB0.y));
      avB[2] = f2bf(__cosf(cB0.z)); avB[3] = f2bf(__cosf(cB0.w));
      avB[4] = f2bf(__cosf(cB1.x)); avB[5] = f2bf(__cosf(cB1.y));
      avB[6] = f2bf(__cosf(cB1.z)); avB[7] = f2bf(__cosf(cB1.w));
    }
    const int mA = a_m, mB = a_m + 32;
    *(short8*)&Ad[mA * BK + (a_il ^ (mA & 7)) * 8] = avA;
    *(short8*)&Ad[mB * BK + (a_il ^ (mB & 7)) * 8] = avB;
  };

  auto stageB = [&](int s, short* __restrict__ Bd) {
    const short* src = bimg + ((size_t)(nt * NSTEPS + s) * BCH2 + t) * 8;
#pragma unroll
    for (int c = 0; c < 8; ++c)
      glds16(src + (size_t)c * 256 * 8, Bd + c * 2048 + wid * 512);
  };

  auto mfma_half = [&](const short* __restrict__ Ab, const short* __restrict__ Bb,
                       int kk) {
    const int sk = kk * 4 + kb;
    short8 af[4], bf[4];
#pragma unroll
    for (int mi = 0; mi < 4; ++mi) {
      const int r = mi * 16 + l15;
      af[mi] = *(const short8*)&Ab[r * BK + (sk ^ (r & 7)) * 8];
    }
#pragma unroll
    for (int ni = 0; ni < 4; ++ni) {
      const int n = wid * 64 + ni * 16 + l15;
      bf[ni] = *(const short8*)&Bb[n * BK + (sk ^ (n & 7)) * 8];
    }
#pragma unroll
    for (int mi = 0; mi < 4; ++mi)
#pragma unroll
      for (int ni = 0; ni < 4; ++ni)
        acc[mi][ni] = __builtin_amdgcn_mfma_f32_16x16x32_bf16(
            af[mi], bf[ni], acc[mi][ni], 0, 0, 0);
  };

  stageB(s0, B_lds[0]);
  loadNext(s0);
  writeA(s0, A_lds[0]);
  __syncthreads();

  for (int si = 0; si < SPLC; ++si) {
    const int c = si & 1;
    const int s = s0 + si;
    if (si + 1 < SPLC) { stageB(s + 1, B_lds[c ^ 1]); loadNext(s + 1); }
    mfma_half(A_lds[c], B_lds[c], 0);
    if (si + 1 < SPLC) writeA(s + 1, A_lds[c ^ 1]);
    mfma_half(A_lds[c], B_lds[c], 1);
    __syncthreads();
  }

#pragma unroll
  for (int ni = 0; ni < 4; ++ni) {
    const int col = n0 + wid * 64 + ni * 16 + l15;
    const float bb = (KS == 1 || ks == 0) ? bias[col] : 0.f;
#pragma unroll
    for (int mi = 0; mi < 4; ++mi) {
      const int rb = m0 + mi * 16 + kb * 4;
#pragma unroll
      for (int r4 = 0; r4 < 4; ++r4) {
        const size_t idx = (size_t)(rb + r4) * OUT_F + col;
        if (KS == 1 || ks == 0) out[idx] = acc[mi][ni][r4] + bb;
        else                    part[idx] = acc[mi][ni][r4];
      }
    }
  }
}

extern "C" void kernel_launch(void* const* d_in, const int* in_sizes, int n_in,
                              void* d_out, int out_size, void* d_ws, size_t ws_size,
                              hipStream_t stream) {
  const float* x    = (const float*)d_in[0];
  const float* rw   = (const float*)d_in[1];
  const float* rc   = (const float*)d_in[2];
  const float* w    = (const float*)d_in[3];
  const float* bias = (const float*)d_in[4];
  const float* sb   = (const float*)d_in[5];
  float* out = (float*)d_out;

  const int nrows = in_sizes[0] / IN_F;  // 8192
  const int npan = nrows / PAN;          // 128 A panels

  const size_t b4_bytes   = (size_t)NT4 * NSTEPS * BCH4 * 16;     // 4.72 MB
  const size_t b2_bytes   = (size_t)NT2 * NSTEPS * BCH2 * 16;     // 4.72 MB
  const size_t aimg_bytes = (size_t)npan * NSTEPS * ACH * 16;     // 75.5 MB
  const size_t part_bytes = (size_t)PART_ELEMS * sizeof(float);   // 16.8 MB

  if (ws_size >= b4_bytes + aimg_bytes + part_bytes) {
    short* bimg = (short*)d_ws;
    short* aimg = (short*)((char*)d_ws + b4_bytes);
    float* part = (float*)((char*)d_ws + b4_bytes + aimg_bytes);
    prep_b4<<<NT4 * NSTEPS * BCH4 / 256, 256, 0, stream>>>(w, sb, bimg);
    prep_a<<<npan * NSTEPS * ACH / 256, 256, 0, stream>>>(x, rw, rc, aimg);
    kan_gemm<2><<<dim3(nrows / 128, 4, 2), 256, 0, stream>>>(aimg, bimg, bias, out, part);
    reduce_add<<<2048, 256, 0, stream>>>(part, out);
  } else if (ws_size >= b4_bytes + aimg_bytes) {
    short* bimg = (short*)d_ws;
    short* aimg = (short*)((char*)d_ws + b4_bytes);
    prep_b4<<<NT4 * NSTEPS * BCH4 / 256, 256, 0, stream>>>(w, sb, bimg);
    prep_a<<<npan * NSTEPS * ACH / 256, 256, 0, stream>>>(x, rw, rc, aimg);
    kan_gemm<1><<<dim3(nrows / 128, 4, 1), 256, 0, stream>>>(aimg, bimg, bias, out, nullptr);
  } else if (ws_size >= b2_bytes + part_bytes) {
    short* bimg = (short*)d_ws;
    float* part = (float*)((char*)d_ws + b2_bytes);
    prep_b2<<<NT2 * NSTEPS * BCH2 / 256, 256, 0, stream>>>(w, sb, bimg);
    kan_fused<2><<<dim3(nrows / 64, NT2, 2), 256, 0, stream>>>(x, rw, rc, bias,
                                                               bimg, out, part);
    reduce_add<<<2048, 256, 0, stream>>>(part, out);
  } else {
    short* bimg = (short*)d_ws;  // requires >= 4.72 MB
    prep_b2<<<NT2 * NSTEPS * BCH2 / 256, 256, 0, stream>>>(w, sb, bimg);
    kan_fused<1><<<dim3(nrows / 64, NT2, 1), 256, 0, stream>>>(x, rw, rc, bias,
                                                               bimg, out, nullptr);
  }
}